// Round 5
// baseline (39455.481 us; speedup 1.0000x reference)
//
#include <hip/hip_runtime.h>
#include <math.h>

#define Bsz 512
#define HID 196
#define REC 488
#define NC  35
#define TT  120
#define G3  1464
#define NSLOT 123         // 4-deep pipeline: s in [0,123)

#define KT   8
#define NCH  61           // 488 = 61*8
#define NB   61           // blocks per GEMM stage (8 cols x 3 gates each)
#define CBLK 64           // cell blocks (8 batch items each)
#define NGRID (3*NB + CBLK)   // 247 blocks <= 256 CUs -> all co-resident

// LDS: GEMM A-chunk double buffer [2][KT][512] = 32768 B; cell overlay smaller.
union SU {
  float a[2*KT*512];
  struct { float xs[8][REC]; float hs[8][36]; float rh[8][36]; } c;
};

__device__ __forceinline__ float sigmoidf_(float x) { return 1.0f / (1.0f + __expf(-x)); }

// ---- software grid barrier (monotonic counter, device-scope) ----
// Release: __threadfence() (agent-scope wbl2) before signal; Acquire:
// __threadfence() (inv) after observing. Polls are atomics -> coherent at LLC,
// immune to per-XCD L2 staleness. Counter zeroed by host memset each call.
__device__ __forceinline__ void gbar(int* bar, int target) {
  __syncthreads();
  if (threadIdx.x == 0) {
    __threadfence();
    atomicAdd(bar, 1);
    while (atomicAdd(bar, 0) < target) __builtin_amdgcn_s_sleep(8);
    __threadfence();
  }
  __syncthreads();
}

// ---- prologue: z = bn(X @ W.T + bias, g, beta) ----
__global__ void dense_bn_kernel(const float* __restrict__ X, const float* __restrict__ W,
                                const float* __restrict__ bias, const float* __restrict__ g,
                                const float* __restrict__ beta, float* __restrict__ Y) {
  __shared__ float xs[HID];
  int b = blockIdx.x;
  for (int k = threadIdx.x; k < HID; k += blockDim.x) xs[k] = X[(size_t)b*HID + k];
  __syncthreads();
  int j = threadIdx.x;
  if (j < HID) {
    const float4* wr = (const float4*)(W + (size_t)j*HID);
    float acc = 0.f;
    #pragma unroll 7
    for (int k4 = 0; k4 < HID/4; ++k4) {
      float4 w4 = wr[k4];
      acc += xs[4*k4+0]*w4.x + xs[4*k4+1]*w4.y + xs[4*k4+2]*w4.z + xs[4*k4+3]*w4.w;
    }
    float v = (acc + bias[j]) * 0.9995003746f;   // 1/sqrt(1+1e-3)
    Y[(size_t)b*HID + j] = g[j]*v + beta[j];
  }
}

// ---- prologue: xg0 = z @ Wih0.T + bih0 (constant over T). 128 blocks x 4 batch ----
__global__ __launch_bounds__(256)
void xg0v2_kernel(const float* __restrict__ Z, const float* __restrict__ Wih,
                  const float* __restrict__ bih, float* __restrict__ XG) {
  __shared__ float zs[HID*4];            // [k][4 items]
  int b0 = blockIdx.x << 2;
  for (int idx = threadIdx.x; idx < HID*4; idx += 256) {
    int k = idx >> 2, i = idx & 3;
    zs[idx] = Z[(size_t)(b0+i)*HID + k];
  }
  __syncthreads();
  for (int c = threadIdx.x; c < G3; c += 256) {
    const float4* wr = (const float4*)(Wih + (size_t)c*HID);
    float a0=0.f,a1=0.f,a2=0.f,a3=0.f;
    for (int k4 = 0; k4 < HID/4; ++k4) {
      float4 w = wr[k4];
      const float* zp = zs + (k4<<4);
      a0=fmaf(w.x,zp[0],a0);  a1=fmaf(w.x,zp[1],a1);  a2=fmaf(w.x,zp[2],a2);  a3=fmaf(w.x,zp[3],a3);
      a0=fmaf(w.y,zp[4],a0);  a1=fmaf(w.y,zp[5],a1);  a2=fmaf(w.y,zp[6],a2);  a3=fmaf(w.y,zp[7],a3);
      a0=fmaf(w.z,zp[8],a0);  a1=fmaf(w.z,zp[9],a1);  a2=fmaf(w.z,zp[10],a2); a3=fmaf(w.z,zp[11],a3);
      a0=fmaf(w.w,zp[12],a0); a1=fmaf(w.w,zp[13],a1); a2=fmaf(w.w,zp[14],a2); a3=fmaf(w.w,zp[15],a3);
    }
    float bb = bih[c];
    XG[(size_t)(b0+0)*G3 + c] = a0 + bb;
    XG[(size_t)(b0+1)*G3 + c] = a1 + bb;
    XG[(size_t)(b0+2)*G3 + c] = a2 + bb;
    XG[(size_t)(b0+3)*G3 + c] = a3 + bb;
  }
}

// ---- prologue: Wt[stage][k][j*24 + g*8 + cl] = W[stage][(g*REC + j*8 + cl)][k] ----
__global__ __launch_bounds__(256)
void wtrans_kernel(const float* __restrict__ Whh0, const float* __restrict__ Wih1,
                   const float* __restrict__ Whh1, float* __restrict__ Wt) {
  int blk = blockIdx.x;                  // 3*61
  int stage = blk / NB, j = blk - stage*NB;
  const float* Wsrc = (stage==0) ? Whh0 : (stage==1) ? Wih1 : Whh1;
  float* dst = Wt + (size_t)stage*REC*G3;
  for (int idx = threadIdx.x; idx < 24*REC; idx += 256) {
    int r = idx / REC, k = idx - r*REC;  // reads coalesced over k
    int g = r >> 3, cl = r & 7;
    dst[(size_t)k*G3 + j*24 + r] = Wsrc[(size_t)(g*REC + j*8 + cl)*REC + k];
  }
}

// ---- acc += A_T[REC][512] (rows rb, rb+64) @ Wt-slice (24 colgates), K=488 ----
// A streamed global->LDS in 16KB chunks, double-buffered; W via wave-uniform
// scalar loads. acc[r*2+i]: r = g*8+cl, row = 128w + l + 64i.
__device__ __forceinline__ void gemm24(const float* __restrict__ AslabT,
                                       const float* __restrict__ Wt, int j,
                                       float* lds, float (&acc)[48])
{
  const int tid = threadIdx.x;
  const int l = tid & 63, w = tid >> 6;
  const int rb = (w << 7) + l;
  float4 hold[4];
  {
    const float4* gsrc = (const float4*)AslabT;
    #pragma unroll
    for (int i = 0; i < 4; ++i) hold[i] = gsrc[tid + (i<<8)];
    float4* d = (float4*)lds;
    #pragma unroll
    for (int i = 0; i < 4; ++i) d[tid + (i<<8)] = hold[i];
  }
  __syncthreads();
  for (int ck = 0; ck < NCH; ++ck) {
    if (ck + 1 < NCH) {
      const float4* gsrc = (const float4*)(AslabT + (size_t)(ck+1)*(KT*512));
      #pragma unroll
      for (int i = 0; i < 4; ++i) hold[i] = gsrc[tid + (i<<8)];
    }
    const float* As = lds + (ck & 1)*(KT*512);
    const float* Wk = Wt + (size_t)ck*KT*G3 + j*24;
    #pragma unroll
    for (int k = 0; k < KT; ++k) {
      float a0 = As[k*512 + rb];
      float a1 = As[k*512 + rb + 64];
      const float* wk = Wk + (size_t)k*G3;
      #pragma unroll
      for (int r = 0; r < 24; ++r) {
        float wv = wk[r];
        acc[r*2+0] = fmaf(a0, wv, acc[r*2+0]);
        acc[r*2+1] = fmaf(a1, wv, acc[r*2+1]);
      }
    }
    if (ck + 1 < NCH) {
      float4* d = (float4*)(lds + ((ck+1)&1)*(KT*512));
      #pragma unroll
      for (int i = 0; i < 4; ++i) d[tid + (i<<8)] = hold[i];
    }
    __syncthreads();
  }
}

// ---- persistent kernel: 4-stage time pipeline, 247 blocks, software barrier ----
// [0,61): GRU0 t=s | [61,122): GRU1 x-pass t=s-1 | [122,183): GRU1 h-pass t=s-2
// | [183,247): cell t=s-3.  States h0T/h1T transposed [c][b]; h1N normal for cell.
__global__ __launch_bounds__(256)
void pers_kernel(const float* __restrict__ xg0,
                 float* __restrict__ h0T, float* __restrict__ h1T,
                 float* __restrict__ h1N, float* __restrict__ xg1,
                 float* __restrict__ hc, float* __restrict__ out,
                 const float* __restrict__ Wt,
                 const float* __restrict__ bhh0,
                 const float* __restrict__ bih1, const float* __restrict__ bhh1,
                 const float* __restrict__ cWih, const float* __restrict__ cWhh,
                 const float* __restrict__ cb, int* __restrict__ bar)
{
  __shared__ SU S;
  const int blk = blockIdx.x;
  const int tid = threadIdx.x;
  const int stage = (blk < NB) ? 0 : (blk < 2*NB) ? 1 : (blk < 3*NB) ? 2 : 3;
  const int l = tid & 63, w = tid >> 6;
  const int rb = (w << 7) + l;

  for (int s = 0; s < NSLOT; ++s) {
    if (stage == 0) {                    // ---------- GRU0, t = s ----------
      if (s < TT) {
        int j = blk;
        const float* hprevT = h0T + (size_t)((s+1)&1)*REC*Bsz;
        float*       hnewT  = h0T + (size_t)(s&1)*REC*Bsz;
        float acc[48] = {0};
        gemm24(hprevT, Wt, j, S.a, acc);
        int c0 = j*8;
        #pragma unroll
        for (int cl = 0; cl < 8; ++cl) {
          int c = c0 + cl;
          float br = bhh0[c], bz = bhh0[REC+c], bn = bhh0[2*REC+c];
          #pragma unroll
          for (int i = 0; i < 2; ++i) {
            int b = rb + (i<<6);
            const float* xr = xg0 + (size_t)b*G3;
            float r = sigmoidf_(xr[c]       + acc[cl*2+i]        + br);
            float z = sigmoidf_(xr[REC+c]   + acc[(8+cl)*2+i]    + bz);
            float n = tanhf   (xr[2*REC+c] + r*(acc[(16+cl)*2+i] + bn));
            hnewT[(size_t)c*Bsz + b] = (1.f-z)*n + z*hprevT[(size_t)c*Bsz + b];
          }
        }
      }
    } else if (stage == 1) {             // ---------- GRU1 x-pass, t = s-1 ----------
      if (s >= 1 && s <= TT) {
        int j = blk - NB;
        int t1 = s - 1;
        const float* xT  = h0T + (size_t)(t1&1)*REC*Bsz;
        float*       xgw = xg1 + (size_t)(t1&1)*Bsz*G3;
        float acc[48] = {0};
        gemm24(xT, Wt + (size_t)REC*G3, j, S.a, acc);
        int c0 = j*8;
        #pragma unroll
        for (int cl = 0; cl < 8; ++cl) {
          int c = c0 + cl;
          #pragma unroll
          for (int i = 0; i < 2; ++i) {
            int b = rb + (i<<6);
            float* o = xgw + (size_t)b*G3;
            o[c]         = acc[cl*2+i];
            o[REC+c]     = acc[(8+cl)*2+i];
            o[2*REC+c]   = acc[(16+cl)*2+i];
          }
        }
      }
    } else if (stage == 2) {             // ---------- GRU1 h-pass, t = s-2 ----------
      if (s >= 2 && s <= TT+1) {
        int j = blk - 2*NB;
        int t2 = s - 2;
        const float* hprevT = h1T + (size_t)((t2+1)&1)*REC*Bsz;
        float*       hnewT  = h1T + (size_t)(t2&1)*REC*Bsz;
        float*       hnewN  = h1N + (size_t)(t2&1)*Bsz*REC;
        const float* xgr    = xg1 + (size_t)(t2&1)*Bsz*G3;
        float acc[48] = {0};
        gemm24(hprevT, Wt + 2*(size_t)REC*G3, j, S.a, acc);
        int c0 = j*8;
        #pragma unroll
        for (int cl = 0; cl < 8; ++cl) {
          int c = c0 + cl;
          float br = bih1[c] + bhh1[c];
          float bz = bih1[REC+c] + bhh1[REC+c];
          float bnx = bih1[2*REC+c], bnh = bhh1[2*REC+c];
          #pragma unroll
          for (int i = 0; i < 2; ++i) {
            int b = rb + (i<<6);
            const float* xr = xgr + (size_t)b*G3;
            float r = sigmoidf_(xr[c]       + acc[cl*2+i]     + br);
            float z = sigmoidf_(xr[REC+c]   + acc[(8+cl)*2+i] + bz);
            float n = tanhf   (xr[2*REC+c] + bnx + r*(acc[(16+cl)*2+i] + bnh));
            float h2 = (1.f-z)*n + z*hprevT[(size_t)c*Bsz + b];
            hnewT[(size_t)c*Bsz + b] = h2;
            hnewN[(size_t)b*REC + c] = h2;
          }
        }
      }
    } else {                             // ---------- custom cell, t = s-3 ----------
      if (s >= 3) {
        int t3 = s - 3;
        int b0 = (blk - 3*NB) << 3;      // 8 items per block
        const float* x  = h1N + (size_t)(t3&1)*Bsz*REC;
        const float* hp = hc  + (size_t)((t3+1)&1)*Bsz*NC;
        float*       hn = hc  + (size_t)(t3&1)*Bsz*NC;
        for (int it = 0; it < 8; ++it)
          for (int k = tid; k < REC; k += 256)
            S.c.xs[it][k] = x[(size_t)(b0+it)*REC + k];
        if (l < NC) {
          #pragma unroll
          for (int q = 0; q < 2; ++q) {
            int it = (w<<1) + q;
            S.c.hs[it][l] = hp[(size_t)(b0+it)*NC + l];
          }
        }
        __syncthreads();
        for (int q = 0; q < 2; ++q) {
          int it = (w<<1) + q;
          int b = b0 + it;
          float v = -1e30f, u = 0.f, hpc = 0.f;
          if (l < NC) {
            const float4* wr4 = (const float4*)(cWih + (size_t)l*REC);
            const float4* wz4 = (const float4*)(cWih + (size_t)(NC+l)*REC);
            const float4* wn4 = (const float4*)(cWih + (size_t)(2*NC+l)*REC);
            const float4* xs4 = (const float4*)(S.c.xs[it]);
            float xr=0.f, xz=0.f, xn=0.f;
            #pragma unroll 2
            for (int k4 = 0; k4 < REC/4; ++k4) {
              float4 xv = xs4[k4];
              float4 wa = wr4[k4], wb = wz4[k4], wc = wn4[k4];
              xr += wa.x*xv.x + wa.y*xv.y + wa.z*xv.z + wa.w*xv.w;
              xz += wb.x*xv.x + wb.y*xv.y + wb.z*xv.z + wb.w*xv.w;
              xn += wc.x*xv.x + wc.y*xv.y + wc.z*xv.z + wc.w*xv.w;
            }
            float hr=0.f, hz=0.f;
            for (int k = 0; k < NC; ++k) {
              float hv = S.c.hs[it][k];
              hr = fmaf(hv, cWhh[(size_t)l*NC + k], hr);
              hz = fmaf(hv, cWhh[(size_t)(NC+l)*NC + k], hz);
            }
            float r = sigmoidf_(xr + hr + cb[l]);
            u       = sigmoidf_(xz + hz + cb[NC+l]);
            hpc = S.c.hs[it][l];
            S.c.rh[it][l] = r * hpc;     // reference: (r*h) @ Whh_n.T
            v = xn;
          }
          __syncthreads();
          if (l < NC) {
            float hnn = 0.f;
            for (int k = 0; k < NC; ++k)
              hnn = fmaf(S.c.rh[it][k], cWhh[(size_t)(2*NC+l)*NC + k], hnn);
            v = v + hnn + cb[2*NC+l];
          }
          float m = v;
          #pragma unroll
          for (int o = 32; o; o >>= 1) m = fmaxf(m, __shfl_xor(m, o));
          float e = (l < NC) ? __expf(v - m) : 0.f;
          float ss = e;
          #pragma unroll
          for (int o = 32; o; o >>= 1) ss += __shfl_xor(ss, o);
          if (l < NC) {
            float h2 = (1.f - u)*(e/ss) + u*hpc;
            hn[(size_t)b*NC + l] = h2;
            out[((size_t)b*TT + t3)*NC + l] = h2;
          }
        }
        __syncthreads();
      }
    }
    gbar(bar, NGRID*(s+1));
  }
}

extern "C" void kernel_launch(void* const* d_in, const int* in_sizes, int n_in,
                              void* d_out, int out_size, void* d_ws, size_t ws_size,
                              hipStream_t stream) {
  const float* z_in  = (const float*)d_in[0];
  const float* W0    = (const float*)d_in[1];
  const float* b0    = (const float*)d_in[2];
  const float* g0    = (const float*)d_in[3];
  const float* beta0 = (const float*)d_in[4];
  const float* W1    = (const float*)d_in[5];
  const float* b1    = (const float*)d_in[6];
  const float* g1    = (const float*)d_in[7];
  const float* beta1 = (const float*)d_in[8];
  const float* Wih0  = (const float*)d_in[9];
  const float* Whh0  = (const float*)d_in[10];
  const float* bih0  = (const float*)d_in[11];
  const float* bhh0  = (const float*)d_in[12];
  const float* Wih1  = (const float*)d_in[13];
  const float* Whh1  = (const float*)d_in[14];
  const float* bih1  = (const float*)d_in[15];
  const float* bhh1  = (const float*)d_in[16];
  const float* cWih  = (const float*)d_in[17];
  const float* cWhh  = (const float*)d_in[18];
  const float* cbih  = (const float*)d_in[19];
  float* out = (float*)d_out;

  float* ws  = (float*)d_ws;
  int*   bar = (int*)ws;                            // 256 floats reserved (zeroed)
  float* h0T = ws  + 256;                           // 2*REC*Bsz   (zeroed)
  float* h1T = h0T + 2*(size_t)REC*Bsz;             // 2*REC*Bsz   (zeroed)
  float* hcb = h1T + 2*(size_t)REC*Bsz;             // 2*Bsz*NC    (zeroed)
  float* h1N = hcb + 2*(size_t)Bsz*NC;              // 2*Bsz*REC
  float* xg1 = h1N + 2*(size_t)Bsz*REC;             // 2*Bsz*G3
  float* xg0 = xg1 + 2*(size_t)Bsz*G3;              // Bsz*G3
  float* z1  = xg0 + (size_t)Bsz*G3;                // Bsz*HID
  float* z2  = z1  + (size_t)Bsz*HID;               // Bsz*HID
  float* Wt  = z2  + (size_t)Bsz*HID;               // 3*REC*G3

  size_t zero_floats = 256 + 4*(size_t)REC*Bsz + 2*(size_t)Bsz*NC;
  hipMemsetAsync(ws, 0, zero_floats*sizeof(float), stream);

  dense_bn_kernel<<<Bsz, 256, 0, stream>>>(z_in, W0, b0, g0, beta0, z1);
  dense_bn_kernel<<<Bsz, 256, 0, stream>>>(z1,   W1, b1, g1, beta1, z2);
  xg0v2_kernel   <<<128, 256, 0, stream>>>(z2, Wih0, bih0, xg0);
  wtrans_kernel  <<<3*NB, 256, 0, stream>>>(Whh0, Wih1, Whh1, Wt);

  pers_kernel<<<NGRID, 256, 0, stream>>>(xg0, h0T, h1T, h1N, xg1, hcb, out,
                                         Wt, bhh0, bih1, bhh1, cWih, cWhh, cbih, bar);
}

// Round 6
// 13773.602 us; speedup vs baseline: 2.8646x; 2.8646x over previous
//
#include <hip/hip_runtime.h>
#include <math.h>

#define Bsz 512
#define HID 196
#define REC 488
#define NC  35
#define TT  120
#define G3  1464
#define NSLOT 123          // 4-deep pipeline: s in [0,123)

#define KT   8
#define NCH  61            // 488 = 61*8
#define NB   61            // blocks per GEMM stage (8 cols x 3 gates each)
#define CELLB 32           // cell blocks (16 batch items each)
#define NGRID (3*NB + CELLB)   // 215 blocks, 512 thr: 1 block/CU, 8 waves/CU
#define WSL  (NCH*KT*24)   // 11712 floats = 46.8 KB per-block weight slice

// LDS: GEMM weight slice (resident all slots) | cell overlay
union SU {
  float w[WSL];
  struct { float xs[16][REC]; float hs[16][36]; float rh[16][36]; } c;
};

__device__ __forceinline__ float sigmoidf_(float x) { return 1.0f / (1.0f + __expf(-x)); }

// ---- software grid barrier: release fence, RMW inc once, LOAD-poll, acquire ----
__device__ __forceinline__ void gbar(int* bar, int target) {
  __syncthreads();
  if (threadIdx.x == 0) {
    __builtin_amdgcn_fence(__ATOMIC_RELEASE, "agent");
    __hip_atomic_fetch_add(bar, 1, __ATOMIC_RELAXED, __HIP_MEMORY_SCOPE_AGENT);
    while (__hip_atomic_load(bar, __ATOMIC_RELAXED, __HIP_MEMORY_SCOPE_AGENT) < target)
      __builtin_amdgcn_s_sleep(2);
    __builtin_amdgcn_fence(__ATOMIC_ACQUIRE, "agent");
  }
  __syncthreads();
}

// ---- prologue: z = bn(X @ W.T + bias, g, beta) ----
__global__ void dense_bn_kernel(const float* __restrict__ X, const float* __restrict__ W,
                                const float* __restrict__ bias, const float* __restrict__ g,
                                const float* __restrict__ beta, float* __restrict__ Y) {
  __shared__ float xs[HID];
  int b = blockIdx.x;
  for (int k = threadIdx.x; k < HID; k += blockDim.x) xs[k] = X[(size_t)b*HID + k];
  __syncthreads();
  int j = threadIdx.x;
  if (j < HID) {
    const float4* wr = (const float4*)(W + (size_t)j*HID);
    float acc = 0.f;
    #pragma unroll 7
    for (int k4 = 0; k4 < HID/4; ++k4) {
      float4 w4 = wr[k4];
      acc += xs[4*k4+0]*w4.x + xs[4*k4+1]*w4.y + xs[4*k4+2]*w4.z + xs[4*k4+3]*w4.w;
    }
    float v = (acc + bias[j]) * 0.9995003746f;   // 1/sqrt(1+1e-3)
    Y[(size_t)b*HID + j] = g[j]*v + beta[j];
  }
}

// ---- prologue: xg0 = z @ Wih0.T + bih0 (constant over T) ----
__global__ __launch_bounds__(256)
void xg0v2_kernel(const float* __restrict__ Z, const float* __restrict__ Wih,
                  const float* __restrict__ bih, float* __restrict__ XG) {
  __shared__ float zs[HID*4];
  int b0 = blockIdx.x << 2;
  for (int idx = threadIdx.x; idx < HID*4; idx += 256) {
    int k = idx >> 2, i = idx & 3;
    zs[idx] = Z[(size_t)(b0+i)*HID + k];
  }
  __syncthreads();
  for (int c = threadIdx.x; c < G3; c += 256) {
    const float4* wr = (const float4*)(Wih + (size_t)c*HID);
    float a0=0.f,a1=0.f,a2=0.f,a3=0.f;
    for (int k4 = 0; k4 < HID/4; ++k4) {
      float4 w = wr[k4];
      const float* zp = zs + (k4<<4);
      a0=fmaf(w.x,zp[0],a0);  a1=fmaf(w.x,zp[1],a1);  a2=fmaf(w.x,zp[2],a2);  a3=fmaf(w.x,zp[3],a3);
      a0=fmaf(w.y,zp[4],a0);  a1=fmaf(w.y,zp[5],a1);  a2=fmaf(w.y,zp[6],a2);  a3=fmaf(w.y,zp[7],a3);
      a0=fmaf(w.z,zp[8],a0);  a1=fmaf(w.z,zp[9],a1);  a2=fmaf(w.z,zp[10],a2); a3=fmaf(w.z,zp[11],a3);
      a0=fmaf(w.w,zp[12],a0); a1=fmaf(w.w,zp[13],a1); a2=fmaf(w.w,zp[14],a2); a3=fmaf(w.w,zp[15],a3);
    }
    float bb = bih[c];
    XG[(size_t)(b0+0)*G3 + c] = a0 + bb;
    XG[(size_t)(b0+1)*G3 + c] = a1 + bb;
    XG[(size_t)(b0+2)*G3 + c] = a2 + bb;
    XG[(size_t)(b0+3)*G3 + c] = a3 + bb;
  }
}

// ---- prologue: per-block contiguous weight slices ----
// Wt2[(stage*NB + j)*WSL + ck*192 + k*24 + (g*8+cl)] = Wsrc[(g*REC + j*8 + cl)*REC + ck*8 + k]
__global__ __launch_bounds__(256)
void wtrans_kernel(const float* __restrict__ Whh0, const float* __restrict__ Wih1,
                   const float* __restrict__ Whh1, float* __restrict__ Wt2) {
  int blk = blockIdx.x;                  // 3*61
  int stage = blk / NB, j = blk - stage*NB;
  const float* Wsrc = (stage==0) ? Whh0 : (stage==1) ? Wih1 : Whh1;
  float* dst = Wt2 + (size_t)blk*WSL;
  for (int idx = threadIdx.x; idx < WSL; idx += 256) {
    int ck = idx / 192, rem = idx - ck*192;
    int k = rem / 24, r = rem - k*24;
    int g = r >> 3, cl = r & 7;
    dst[idx] = Wsrc[(size_t)(g*REC + j*8 + cl)*REC + ck*8 + k];
  }
}

// ---- acc[24] += A[row][0..488] @ Wlds(24 colgates): no LDS staging of A,
// no barriers; depth-2 register prefetch; weights via broadcast ds_read_b128.
__device__ __forceinline__ void gemm24d(const float* __restrict__ ar,
                                        const float* __restrict__ Wl,
                                        float (&acc)[24])
{
  float4 p0 = *(const float4*)(ar);
  float4 p1 = *(const float4*)(ar + 4);
  float4 q0 = *(const float4*)(ar + 8);
  float4 q1 = *(const float4*)(ar + 12);
  for (int ck = 0; ck < NCH; ++ck) {
    float av[8] = {p0.x,p0.y,p0.z,p0.w,p1.x,p1.y,p1.z,p1.w};
    p0 = q0; p1 = q1;
    if (ck + 2 < NCH) {
      q0 = *(const float4*)(ar + (ck+2)*KT);
      q1 = *(const float4*)(ar + (ck+2)*KT + 4);
    }
    const float* wp = Wl + ck*192;
    #pragma unroll
    for (int k = 0; k < KT; ++k) {
      float a = av[k];
      const float4* w4 = (const float4*)(wp + k*24);
      #pragma unroll
      for (int r4 = 0; r4 < 6; ++r4) {
        float4 w = w4[r4];
        acc[r4*4+0] = fmaf(a, w.x, acc[r4*4+0]);
        acc[r4*4+1] = fmaf(a, w.y, acc[r4*4+1]);
        acc[r4*4+2] = fmaf(a, w.z, acc[r4*4+2]);
        acc[r4*4+3] = fmaf(a, w.w, acc[r4*4+3]);
      }
    }
  }
}

// ---- persistent kernel: 4-stage time pipeline, 215 blocks x 512 threads ----
// [0,61): GRU0 t=s | [61,122): GRU1 x-pass t=s-1 | [122,183): GRU1 h-pass t=s-2
// | [183,215): cell t=s-3.  All states normal layout [b][c].
__global__ __launch_bounds__(512)
void pers_kernel(const float* __restrict__ xg0,
                 float* __restrict__ h0, float* __restrict__ h1,
                 float* __restrict__ xg1, float* __restrict__ hc,
                 float* __restrict__ out,
                 const float* __restrict__ Wt2,
                 const float* __restrict__ bhh0,
                 const float* __restrict__ bih1, const float* __restrict__ bhh1,
                 const float* __restrict__ cWih, const float* __restrict__ cWhh,
                 const float* __restrict__ cb, int* __restrict__ bar)
{
  __shared__ SU S;
  const int blk = blockIdx.x;
  const int tid = threadIdx.x;
  const int stage = (blk < NB) ? 0 : (blk < 2*NB) ? 1 : (blk < 3*NB) ? 2 : 3;

  // stage weight slice into LDS once; survives all slots (acquire-inv doesn't touch LDS)
  if (stage <= 2) {
    const float* src = Wt2 + (size_t)blk*WSL;
    for (int idx = tid; idx < WSL; idx += 512) S.w[idx] = src[idx];
  }
  __syncthreads();

  const int l = tid & 63, w = tid >> 6;

  for (int s = 0; s < NSLOT; ++s) {
    if (stage == 0) {                    // ---------- GRU0, t = s ----------
      if (s < TT) {
        int j = blk;
        const float* hprev = h0 + (size_t)((s+1)&1)*Bsz*REC;
        float*       hnew  = h0 + (size_t)(s&1)*Bsz*REC;
        float acc[24] = {0};
        gemm24d(hprev + (size_t)tid*REC, S.w, acc);
        int b = tid, c0 = j*8;
        const float* xr = xg0 + (size_t)b*G3;
        #pragma unroll
        for (int cl = 0; cl < 8; ++cl) {
          int c = c0 + cl;
          float r = sigmoidf_(xr[c]       + acc[cl]      + bhh0[c]);
          float z = sigmoidf_(xr[REC+c]   + acc[8+cl]    + bhh0[REC+c]);
          float n = tanhf   (xr[2*REC+c] + r*(acc[16+cl] + bhh0[2*REC+c]));
          hnew[(size_t)b*REC + c] = (1.f-z)*n + z*hprev[(size_t)b*REC + c];
        }
      }
    } else if (stage == 1) {             // ---------- GRU1 x-pass, t = s-1 ----------
      if (s >= 1 && s <= TT) {
        int j = blk - NB;
        int t1 = s - 1;
        const float* x   = h0  + (size_t)(t1&1)*Bsz*REC;
        float*       xgw = xg1 + (size_t)(t1&1)*Bsz*G3;
        float acc[24] = {0};
        gemm24d(x + (size_t)tid*REC, S.w, acc);
        int b = tid, c0 = j*8;
        float* o = xgw + (size_t)b*G3;
        #pragma unroll
        for (int cl = 0; cl < 8; ++cl) {
          int c = c0 + cl;
          o[c] = acc[cl]; o[REC+c] = acc[8+cl]; o[2*REC+c] = acc[16+cl];
        }
      }
    } else if (stage == 2) {             // ---------- GRU1 h-pass, t = s-2 ----------
      if (s >= 2 && s <= TT+1) {
        int j = blk - 2*NB;
        int t2 = s - 2;
        const float* hprev = h1  + (size_t)((t2+1)&1)*Bsz*REC;
        float*       hnew  = h1  + (size_t)(t2&1)*Bsz*REC;
        const float* xgr   = xg1 + (size_t)(t2&1)*Bsz*G3;
        float acc[24] = {0};
        gemm24d(hprev + (size_t)tid*REC, S.w, acc);
        int b = tid, c0 = j*8;
        const float* xr = xgr + (size_t)b*G3;
        #pragma unroll
        for (int cl = 0; cl < 8; ++cl) {
          int c = c0 + cl;
          float r = sigmoidf_(xr[c]       + acc[cl]   + bih1[c]     + bhh1[c]);
          float z = sigmoidf_(xr[REC+c]   + acc[8+cl] + bih1[REC+c] + bhh1[REC+c]);
          float n = tanhf   (xr[2*REC+c] + bih1[2*REC+c] + r*(acc[16+cl] + bhh1[2*REC+c]));
          hnew[(size_t)b*REC + c] = (1.f-z)*n + z*hprev[(size_t)b*REC + c];
        }
      }
    } else {                             // ---------- custom cell, t = s-3 ----------
      if (s >= 3) {
        int t3 = s - 3;
        int b0 = (blk - 3*NB) << 4;      // 16 items per block
        const float* x  = h1 + (size_t)(t3&1)*Bsz*REC;
        const float* hp = hc + (size_t)((t3+1)&1)*Bsz*NC;
        float*       hn = hc + (size_t)(t3&1)*Bsz*NC;
        for (int idx = tid; idx < 16*REC; idx += 512) {
          int it = idx / REC, k = idx - it*REC;
          S.c.xs[it][k] = x[(size_t)(b0+it)*REC + k];
        }
        if (l < NC) {
          #pragma unroll
          for (int q = 0; q < 2; ++q) {
            int it = (w<<1) + q;
            S.c.hs[it][l] = hp[(size_t)(b0+it)*NC + l];
          }
        }
        __syncthreads();
        for (int q = 0; q < 2; ++q) {
          int it = (w<<1) + q;
          int b = b0 + it;
          float v = -1e30f, u = 0.f, hpc = 0.f;
          if (l < NC) {
            const float4* wr4 = (const float4*)(cWih + (size_t)l*REC);
            const float4* wz4 = (const float4*)(cWih + (size_t)(NC+l)*REC);
            const float4* wn4 = (const float4*)(cWih + (size_t)(2*NC+l)*REC);
            const float4* xs4 = (const float4*)(S.c.xs[it]);
            float xr=0.f, xz=0.f, xn=0.f;
            #pragma unroll 2
            for (int k4 = 0; k4 < REC/4; ++k4) {
              float4 xv = xs4[k4];
              float4 wa = wr4[k4], wb = wz4[k4], wc = wn4[k4];
              xr += wa.x*xv.x + wa.y*xv.y + wa.z*xv.z + wa.w*xv.w;
              xz += wb.x*xv.x + wb.y*xv.y + wb.z*xv.z + wb.w*xv.w;
              xn += wc.x*xv.x + wc.y*xv.y + wc.z*xv.z + wc.w*xv.w;
            }
            float hr=0.f, hz=0.f;
            for (int k = 0; k < NC; ++k) {
              float hv = S.c.hs[it][k];
              hr = fmaf(hv, cWhh[(size_t)l*NC + k], hr);
              hz = fmaf(hv, cWhh[(size_t)(NC+l)*NC + k], hz);
            }
            float r = sigmoidf_(xr + hr + cb[l]);
            u       = sigmoidf_(xz + hz + cb[NC+l]);
            hpc = S.c.hs[it][l];
            S.c.rh[it][l] = r * hpc;     // reference: (r*h) @ Whh_n.T
            v = xn;
          }
          __syncthreads();
          if (l < NC) {
            float hnn = 0.f;
            for (int k = 0; k < NC; ++k)
              hnn = fmaf(S.c.rh[it][k], cWhh[(size_t)(2*NC+l)*NC + k], hnn);
            v = v + hnn + cb[2*NC+l];
          }
          float m = v;
          #pragma unroll
          for (int o = 32; o; o >>= 1) m = fmaxf(m, __shfl_xor(m, o));
          float e = (l < NC) ? __expf(v - m) : 0.f;
          float ss = e;
          #pragma unroll
          for (int o = 32; o; o >>= 1) ss += __shfl_xor(ss, o);
          if (l < NC) {
            float h2 = (1.f - u)*(e/ss) + u*hpc;
            hn[(size_t)b*NC + l] = h2;
            out[((size_t)b*TT + t3)*NC + l] = h2;
          }
          __syncthreads();
        }
      }
    }
    gbar(bar, NGRID*(s+1));
  }
}

extern "C" void kernel_launch(void* const* d_in, const int* in_sizes, int n_in,
                              void* d_out, int out_size, void* d_ws, size_t ws_size,
                              hipStream_t stream) {
  const float* z_in  = (const float*)d_in[0];
  const float* W0    = (const float*)d_in[1];
  const float* b0    = (const float*)d_in[2];
  const float* g0    = (const float*)d_in[3];
  const float* beta0 = (const float*)d_in[4];
  const float* W1    = (const float*)d_in[5];
  const float* b1    = (const float*)d_in[6];
  const float* g1    = (const float*)d_in[7];
  const float* beta1 = (const float*)d_in[8];
  const float* Wih0  = (const float*)d_in[9];
  const float* Whh0  = (const float*)d_in[10];
  const float* bih0  = (const float*)d_in[11];
  const float* bhh0  = (const float*)d_in[12];
  const float* Wih1  = (const float*)d_in[13];
  const float* Whh1  = (const float*)d_in[14];
  const float* bih1  = (const float*)d_in[15];
  const float* bhh1  = (const float*)d_in[16];
  const float* cWih  = (const float*)d_in[17];
  const float* cWhh  = (const float*)d_in[18];
  const float* cbih  = (const float*)d_in[19];
  float* out = (float*)d_out;

  float* ws  = (float*)d_ws;
  int*   bar = (int*)ws;                            // 256 slots (zeroed)
  float* h0  = ws  + 256;                           // 2*Bsz*REC (zeroed)
  float* h1  = h0  + 2*(size_t)Bsz*REC;             // 2*Bsz*REC (zeroed)
  float* hcb = h1  + 2*(size_t)Bsz*REC;             // 2*Bsz*NC  (zeroed)
  float* xg1 = hcb + 2*(size_t)Bsz*NC;              // 2*Bsz*G3
  float* xg0 = xg1 + 2*(size_t)Bsz*G3;              // Bsz*G3
  float* z1  = xg0 + (size_t)Bsz*G3;                // Bsz*HID
  float* z2  = z1  + (size_t)Bsz*HID;               // Bsz*HID
  float* Wt2 = z2  + (size_t)Bsz*HID;               // 3*NB*WSL = 8.6 MB

  size_t zero_floats = 256 + 4*(size_t)Bsz*REC + 2*(size_t)Bsz*NC;
  hipMemsetAsync(ws, 0, zero_floats*sizeof(float), stream);

  dense_bn_kernel<<<Bsz, 256, 0, stream>>>(z_in, W0, b0, g0, beta0, z1);
  dense_bn_kernel<<<Bsz, 256, 0, stream>>>(z1,   W1, b1, g1, beta1, z2);
  xg0v2_kernel   <<<128, 256, 0, stream>>>(z2, Wih0, bih0, xg0);
  wtrans_kernel  <<<3*NB, 256, 0, stream>>>(Whh0, Wih1, Whh1, Wt2);

  pers_kernel<<<NGRID, 512, 0, stream>>>(xg0, h0, h1, xg1, hcb, out,
                                         Wt2, bhh0, bih1, bhh1, cWih, cWhh, cbih, bar);
}

// Round 7
// 12441.753 us; speedup vs baseline: 3.1712x; 1.1070x over previous
//
#include <hip/hip_runtime.h>
#include <math.h>

#define Bsz 512
#define HID 196
#define REC 488
#define NC  35
#define TT  120
#define G3  1464
#define NSLOT 123          // 4-deep pipeline: s in [0,123)

#define KT   8
#define NCH  61            // 488 = 61*8
#define NB   61            // blocks per GEMM stage (8 cols x 3 gates each)
#define CELLB 32           // cell blocks (16 batch items each)
#define NGRID (3*NB + CELLB)   // 215 blocks, 512 thr: 1 block/CU, 8 waves/CU
#define WSL  (NCH*KT*24)   // 11712 floats = 46.8 KB per-block weight slice

// LDS: GEMM weight slice (resident all slots) | cell overlay (35.8 KB)
union SU {
  float w[WSL];
  struct { float xs[16][REC]; float hs[16][36]; float rh[16][36]; } c;
};

__device__ __forceinline__ float sigmoidf_(float x) { return 1.0f / (1.0f + __expf(-x)); }

// ---- software grid barrier: release fence, RMW inc once, LOAD-poll, acquire ----
__device__ __forceinline__ void gbar(int* bar, int target) {
  __syncthreads();
  if (threadIdx.x == 0) {
    __builtin_amdgcn_fence(__ATOMIC_RELEASE, "agent");
    __hip_atomic_fetch_add(bar, 1, __ATOMIC_RELAXED, __HIP_MEMORY_SCOPE_AGENT);
    while (__hip_atomic_load(bar, __ATOMIC_RELAXED, __HIP_MEMORY_SCOPE_AGENT) < target)
      __builtin_amdgcn_s_sleep(2);
    __builtin_amdgcn_fence(__ATOMIC_ACQUIRE, "agent");
  }
  __syncthreads();
}

// ---- prologue: z = bn(X @ W.T + bias, g, beta) ----
__global__ void dense_bn_kernel(const float* __restrict__ X, const float* __restrict__ W,
                                const float* __restrict__ bias, const float* __restrict__ g,
                                const float* __restrict__ beta, float* __restrict__ Y) {
  __shared__ float xs[HID];
  int b = blockIdx.x;
  for (int k = threadIdx.x; k < HID; k += blockDim.x) xs[k] = X[(size_t)b*HID + k];
  __syncthreads();
  int j = threadIdx.x;
  if (j < HID) {
    const float4* wr = (const float4*)(W + (size_t)j*HID);
    float acc = 0.f;
    #pragma unroll 7
    for (int k4 = 0; k4 < HID/4; ++k4) {
      float4 w4 = wr[k4];
      acc += xs[4*k4+0]*w4.x + xs[4*k4+1]*w4.y + xs[4*k4+2]*w4.z + xs[4*k4+3]*w4.w;
    }
    float v = (acc + bias[j]) * 0.9995003746f;   // 1/sqrt(1+1e-3)
    Y[(size_t)b*HID + j] = g[j]*v + beta[j];
  }
}

// ---- prologue: xg0T[c][b] = (z @ Wih0.T + bih0)^T  (constant over T) ----
__global__ __launch_bounds__(256)
void xg0v2_kernel(const float* __restrict__ Z, const float* __restrict__ Wih,
                  const float* __restrict__ bih, float* __restrict__ XGT) {
  __shared__ float zs[HID*4];
  int b0 = blockIdx.x << 2;
  for (int idx = threadIdx.x; idx < HID*4; idx += 256) {
    int k = idx >> 2, i = idx & 3;
    zs[idx] = Z[(size_t)(b0+i)*HID + k];
  }
  __syncthreads();
  for (int c = threadIdx.x; c < G3; c += 256) {
    const float4* wr = (const float4*)(Wih + (size_t)c*HID);
    float a0=0.f,a1=0.f,a2=0.f,a3=0.f;
    for (int k4 = 0; k4 < HID/4; ++k4) {
      float4 w = wr[k4];
      const float* zp = zs + (k4<<4);
      a0=fmaf(w.x,zp[0],a0);  a1=fmaf(w.x,zp[1],a1);  a2=fmaf(w.x,zp[2],a2);  a3=fmaf(w.x,zp[3],a3);
      a0=fmaf(w.y,zp[4],a0);  a1=fmaf(w.y,zp[5],a1);  a2=fmaf(w.y,zp[6],a2);  a3=fmaf(w.y,zp[7],a3);
      a0=fmaf(w.z,zp[8],a0);  a1=fmaf(w.z,zp[9],a1);  a2=fmaf(w.z,zp[10],a2); a3=fmaf(w.z,zp[11],a3);
      a0=fmaf(w.w,zp[12],a0); a1=fmaf(w.w,zp[13],a1); a2=fmaf(w.w,zp[14],a2); a3=fmaf(w.w,zp[15],a3);
    }
    float bb = bih[c];
    XGT[(size_t)c*Bsz + b0+0] = a0 + bb;
    XGT[(size_t)c*Bsz + b0+1] = a1 + bb;
    XGT[(size_t)c*Bsz + b0+2] = a2 + bb;
    XGT[(size_t)c*Bsz + b0+3] = a3 + bb;
  }
}

// ---- prologue: per-block contiguous weight slices ----
// Wt2[(stage*NB + j)*WSL + ck*192 + k*24 + (g*8+cl)] = Wsrc[(g*REC + j*8 + cl)*REC + ck*8 + k]
__global__ __launch_bounds__(256)
void wtrans_kernel(const float* __restrict__ Whh0, const float* __restrict__ Wih1,
                   const float* __restrict__ Whh1, float* __restrict__ Wt2) {
  int blk = blockIdx.x;                  // 3*61
  int stage = blk / NB, j = blk - stage*NB;
  const float* Wsrc = (stage==0) ? Whh0 : (stage==1) ? Wih1 : Whh1;
  float* dst = Wt2 + (size_t)blk*WSL;
  for (int idx = threadIdx.x; idx < WSL; idx += 256) {
    int ck = idx / 192, rem = idx - ck*192;
    int k = rem / 24, r = rem - k*24;
    int g = r >> 3, cl = r & 7;
    dst[idx] = Wsrc[(size_t)(g*REC + j*8 + cl)*REC + ck*8 + k];
  }
}

// ---- acc[24] += AT[:,b] @ Wlds(24 colgates), K=488 ----
// AT layout [k][512]: per-k loads are wave-coalesced (64 consecutive dwords).
// Depth-1 chunk prefetch in registers; weights via broadcast ds_read_b128.
__device__ __forceinline__ void gemm24t(const float* __restrict__ AT, int b,
                                        const float* __restrict__ Wl,
                                        float (&acc)[24])
{
  float av[KT], nv[KT];
  #pragma unroll
  for (int k = 0; k < KT; ++k) av[k] = AT[(size_t)k*Bsz + b];
  for (int ck = 0; ck < NCH; ++ck) {
    if (ck + 1 < NCH) {
      const float* src = AT + (size_t)(ck+1)*KT*Bsz + b;
      #pragma unroll
      for (int k = 0; k < KT; ++k) nv[k] = src[(size_t)k*Bsz];
    }
    const float* wp = Wl + ck*192;
    #pragma unroll
    for (int k = 0; k < KT; ++k) {
      float a = av[k];
      const float4* w4 = (const float4*)(wp + k*24);
      #pragma unroll
      for (int r4 = 0; r4 < 6; ++r4) {
        float4 w = w4[r4];
        acc[r4*4+0] = fmaf(a, w.x, acc[r4*4+0]);
        acc[r4*4+1] = fmaf(a, w.y, acc[r4*4+1]);
        acc[r4*4+2] = fmaf(a, w.z, acc[r4*4+2]);
        acc[r4*4+3] = fmaf(a, w.w, acc[r4*4+3]);
      }
    }
    #pragma unroll
    for (int k = 0; k < KT; ++k) av[k] = nv[k];
  }
}

// ---- persistent kernel: 4-stage time pipeline, 215 blocks x 512 threads ----
// [0,61): GRU0 t=s | [61,122): GRU1 x-pass t=s-1 | [122,183): GRU1 h-pass t=s-2
// | [183,215): cell t=s-3.  Recurrent states TRANSPOSED [c][b]; hc normal.
__global__ __launch_bounds__(512)
void pers_kernel(const float* __restrict__ xg0T,
                 float* __restrict__ h0T, float* __restrict__ h1T,
                 float* __restrict__ xg1T, float* __restrict__ hc,
                 float* __restrict__ out,
                 const float* __restrict__ Wt2,
                 const float* __restrict__ bhh0,
                 const float* __restrict__ bih1, const float* __restrict__ bhh1,
                 const float* __restrict__ cWih, const float* __restrict__ cWhh,
                 const float* __restrict__ cb, int* __restrict__ bar)
{
  __shared__ SU S;
  const int blk = blockIdx.x;
  const int tid = threadIdx.x;
  const int stage = (blk < NB) ? 0 : (blk < 2*NB) ? 1 : (blk < 3*NB) ? 2 : 3;

  // stage weight slice into LDS once; survives all slots
  if (stage <= 2) {
    const float* src = Wt2 + (size_t)blk*WSL;
    for (int idx = tid; idx < WSL; idx += 512) S.w[idx] = src[idx];
  }
  __syncthreads();

  const int l = tid & 63, w = tid >> 6;

  for (int s = 0; s < NSLOT; ++s) {
    if (stage == 0) {                    // ---------- GRU0, t = s ----------
      if (s < TT) {
        int j = blk;
        const float* hprevT = h0T + (size_t)((s+1)&1)*REC*Bsz;
        float*       hnewT  = h0T + (size_t)(s&1)*REC*Bsz;
        float acc[24] = {0};
        gemm24t(hprevT, tid, S.w, acc);
        int b = tid, c0 = j*8;
        #pragma unroll
        for (int cl = 0; cl < 8; ++cl) {
          int c = c0 + cl;
          float xrv = xg0T[(size_t)c*Bsz + b];
          float xzv = xg0T[(size_t)(REC+c)*Bsz + b];
          float xnv = xg0T[(size_t)(2*REC+c)*Bsz + b];
          float r = sigmoidf_(xrv + acc[cl]      + bhh0[c]);
          float z = sigmoidf_(xzv + acc[8+cl]    + bhh0[REC+c]);
          float n = tanhf   (xnv + r*(acc[16+cl] + bhh0[2*REC+c]));
          hnewT[(size_t)c*Bsz + b] = (1.f-z)*n + z*hprevT[(size_t)c*Bsz + b];
        }
      }
    } else if (stage == 1) {             // ---------- GRU1 x-pass, t = s-1 ----------
      if (s >= 1 && s <= TT) {
        int j = blk - NB;
        int t1 = s - 1;
        const float* xT   = h0T  + (size_t)(t1&1)*REC*Bsz;
        float*       xgwT = xg1T + (size_t)(t1&1)*G3*Bsz;
        float acc[24] = {0};
        gemm24t(xT, tid, S.w, acc);
        int b = tid, c0 = j*8;
        #pragma unroll
        for (int cl = 0; cl < 8; ++cl) {
          int c = c0 + cl;
          xgwT[(size_t)c*Bsz + b]         = acc[cl];
          xgwT[(size_t)(REC+c)*Bsz + b]   = acc[8+cl];
          xgwT[(size_t)(2*REC+c)*Bsz + b] = acc[16+cl];
        }
      }
    } else if (stage == 2) {             // ---------- GRU1 h-pass, t = s-2 ----------
      if (s >= 2 && s <= TT+1) {
        int j = blk - 2*NB;
        int t2 = s - 2;
        const float* hprevT = h1T  + (size_t)((t2+1)&1)*REC*Bsz;
        float*       hnewT  = h1T  + (size_t)(t2&1)*REC*Bsz;
        const float* xgrT   = xg1T + (size_t)(t2&1)*G3*Bsz;
        float acc[24] = {0};
        gemm24t(hprevT, tid, S.w, acc);
        int b = tid, c0 = j*8;
        #pragma unroll
        for (int cl = 0; cl < 8; ++cl) {
          int c = c0 + cl;
          float xrv = xgrT[(size_t)c*Bsz + b];
          float xzv = xgrT[(size_t)(REC+c)*Bsz + b];
          float xnv = xgrT[(size_t)(2*REC+c)*Bsz + b];
          float r = sigmoidf_(xrv + acc[cl]   + bih1[c]     + bhh1[c]);
          float z = sigmoidf_(xzv + acc[8+cl] + bih1[REC+c] + bhh1[REC+c]);
          float n = tanhf   (xnv + bih1[2*REC+c] + r*(acc[16+cl] + bhh1[2*REC+c]));
          hnewT[(size_t)c*Bsz + b] = (1.f-z)*n + z*hprevT[(size_t)c*Bsz + b];
        }
      }
    } else {                             // ---------- custom cell, t = s-3 ----------
      if (s >= 3) {
        int t3 = s - 3;
        int b0 = (blk - 3*NB) << 4;      // 16 items per block
        const float* xT = h1T + (size_t)(t3&1)*REC*Bsz;
        const float* hp = hc  + (size_t)((t3+1)&1)*Bsz*NC;
        float*       hn = hc  + (size_t)(t3&1)*Bsz*NC;
        // stage x rows from transposed slab: idx = [k][it], 16-lane segments
        for (int idx = tid; idx < 16*REC; idx += 512) {
          int k = idx >> 4, it = idx & 15;
          S.c.xs[it][k] = xT[(size_t)k*Bsz + b0 + it];
        }
        if (l < NC) {
          #pragma unroll
          for (int q = 0; q < 2; ++q) {
            int it = (w<<1) + q;
            S.c.hs[it][l] = hp[(size_t)(b0+it)*NC + l];
          }
        }
        __syncthreads();
        for (int q = 0; q < 2; ++q) {
          int it = (w<<1) + q;
          int b = b0 + it;
          float v = -1e30f, u = 0.f, hpc = 0.f;
          if (l < NC) {
            const float4* wr4 = (const float4*)(cWih + (size_t)l*REC);
            const float4* wz4 = (const float4*)(cWih + (size_t)(NC+l)*REC);
            const float4* wn4 = (const float4*)(cWih + (size_t)(2*NC+l)*REC);
            const float4* xs4 = (const float4*)(S.c.xs[it]);
            float xr=0.f, xz=0.f, xn=0.f;
            #pragma unroll 2
            for (int k4 = 0; k4 < REC/4; ++k4) {
              float4 xv = xs4[k4];
              float4 wa = wr4[k4], wb = wz4[k4], wc = wn4[k4];
              xr += wa.x*xv.x + wa.y*xv.y + wa.z*xv.z + wa.w*xv.w;
              xz += wb.x*xv.x + wb.y*xv.y + wb.z*xv.z + wb.w*xv.w;
              xn += wc.x*xv.x + wc.y*xv.y + wc.z*xv.z + wc.w*xv.w;
            }
            float hr=0.f, hz=0.f;
            for (int k = 0; k < NC; ++k) {
              float hv = S.c.hs[it][k];
              hr = fmaf(hv, cWhh[(size_t)l*NC + k], hr);
              hz = fmaf(hv, cWhh[(size_t)(NC+l)*NC + k], hz);
            }
            float r = sigmoidf_(xr + hr + cb[l]);
            u       = sigmoidf_(xz + hz + cb[NC+l]);
            hpc = S.c.hs[it][l];
            S.c.rh[it][l] = r * hpc;     // reference: (r*h) @ Whh_n.T
            v = xn;
          }
          __syncthreads();
          if (l < NC) {
            float hnn = 0.f;
            for (int k = 0; k < NC; ++k)
              hnn = fmaf(S.c.rh[it][k], cWhh[(size_t)(2*NC+l)*NC + k], hnn);
            v = v + hnn + cb[2*NC+l];
          }
          float m = v;
          #pragma unroll
          for (int o = 32; o; o >>= 1) m = fmaxf(m, __shfl_xor(m, o));
          float e = (l < NC) ? __expf(v - m) : 0.f;
          float ss = e;
          #pragma unroll
          for (int o = 32; o; o >>= 1) ss += __shfl_xor(ss, o);
          if (l < NC) {
            float h2 = (1.f - u)*(e/ss) + u*hpc;
            hn[(size_t)b*NC + l] = h2;
            out[((size_t)b*TT + t3)*NC + l] = h2;
          }
          __syncthreads();
        }
      }
    }
    gbar(bar, NGRID*(s+1));
  }
}

extern "C" void kernel_launch(void* const* d_in, const int* in_sizes, int n_in,
                              void* d_out, int out_size, void* d_ws, size_t ws_size,
                              hipStream_t stream) {
  const float* z_in  = (const float*)d_in[0];
  const float* W0    = (const float*)d_in[1];
  const float* b0    = (const float*)d_in[2];
  const float* g0    = (const float*)d_in[3];
  const float* beta0 = (const float*)d_in[4];
  const float* W1    = (const float*)d_in[5];
  const float* b1    = (const float*)d_in[6];
  const float* g1    = (const float*)d_in[7];
  const float* beta1 = (const float*)d_in[8];
  const float* Wih0  = (const float*)d_in[9];
  const float* Whh0  = (const float*)d_in[10];
  const float* bih0  = (const float*)d_in[11];
  const float* bhh0  = (const float*)d_in[12];
  const float* Wih1  = (const float*)d_in[13];
  const float* Whh1  = (const float*)d_in[14];
  const float* bih1  = (const float*)d_in[15];
  const float* bhh1  = (const float*)d_in[16];
  const float* cWih  = (const float*)d_in[17];
  const float* cWhh  = (const float*)d_in[18];
  const float* cbih  = (const float*)d_in[19];
  float* out = (float*)d_out;

  float* ws   = (float*)d_ws;
  int*   bar  = (int*)ws;                            // 256 slots (zeroed)
  float* h0T  = ws   + 256;                          // 2*REC*Bsz (zeroed)
  float* h1T  = h0T  + 2*(size_t)REC*Bsz;            // 2*REC*Bsz (zeroed)
  float* hcb  = h1T  + 2*(size_t)REC*Bsz;            // 2*Bsz*NC  (zeroed)
  float* xg1T = hcb  + 2*(size_t)Bsz*NC;             // 2*G3*Bsz
  float* xg0T = xg1T + 2*(size_t)G3*Bsz;             // G3*Bsz
  float* z1   = xg0T + (size_t)G3*Bsz;               // Bsz*HID
  float* z2   = z1   + (size_t)Bsz*HID;              // Bsz*HID
  float* Wt2  = z2   + (size_t)Bsz*HID;              // 3*NB*WSL = 8.6 MB

  size_t zero_floats = 256 + 4*(size_t)REC*Bsz + 2*(size_t)Bsz*NC;
  hipMemsetAsync(ws, 0, zero_floats*sizeof(float), stream);

  dense_bn_kernel<<<Bsz, 256, 0, stream>>>(z_in, W0, b0, g0, beta0, z1);
  dense_bn_kernel<<<Bsz, 256, 0, stream>>>(z1,   W1, b1, g1, beta1, z2);
  xg0v2_kernel   <<<128, 256, 0, stream>>>(z2, Wih0, bih0, xg0T);
  wtrans_kernel  <<<3*NB, 256, 0, stream>>>(Whh0, Wih1, Whh1, Wt2);

  pers_kernel<<<NGRID, 512, 0, stream>>>(xg0T, h0T, h1T, xg1T, hcb, out,
                                         Wt2, bhh0, bih1, bhh1, cWih, cWhh, cbih, bar);
}

// Round 8
// 11720.216 us; speedup vs baseline: 3.3664x; 1.0616x over previous
//
#include <hip/hip_runtime.h>
#include <math.h>

#define Bsz 512
#define HID 196
#define REC 488
#define NC  35
#define TT  120
#define G3  1464
#define NSLOT 123          // 4-deep pipeline: s in [0,123)

#define KT   8
#define NCH  61            // 488 = 61*8
#define NB   61            // blocks per GEMM stage (8 cols x 3 gates each)
#define CELLB 32           // cell blocks (16 batch items each)
#define NGRID (3*NB + CELLB)   // 215 blocks, 512 thr: 1 block/CU, 8 waves/CU
#define WSL  (NCH*KT*24)   // 11712 floats = 46.8 KB per-block weight slice

// LDS: only the cell blocks use it (GEMM weights now ride the scalar pipe).
// xs row stride 492 keeps staging writes at <=2-way bank aliasing (free).
struct CellSmem { float xs[16][492]; float hs[16][36]; float rh[16][36]; };

__device__ __forceinline__ float sigmoidf_(float x) { return 1.0f / (1.0f + __expf(-x)); }

// ---- software grid barrier: release fence, RMW inc once, LOAD-poll, acquire ----
__device__ __forceinline__ void gbar(int* bar, int target) {
  __syncthreads();
  if (threadIdx.x == 0) {
    __builtin_amdgcn_fence(__ATOMIC_RELEASE, "agent");
    __hip_atomic_fetch_add(bar, 1, __ATOMIC_RELAXED, __HIP_MEMORY_SCOPE_AGENT);
    while (__hip_atomic_load(bar, __ATOMIC_RELAXED, __HIP_MEMORY_SCOPE_AGENT) < target)
      __builtin_amdgcn_s_sleep(2);
    __builtin_amdgcn_fence(__ATOMIC_ACQUIRE, "agent");
  }
  __syncthreads();
}

// ---- prologue: z = bn(X @ W.T + bias, g, beta) ----
__global__ void dense_bn_kernel(const float* __restrict__ X, const float* __restrict__ W,
                                const float* __restrict__ bias, const float* __restrict__ g,
                                const float* __restrict__ beta, float* __restrict__ Y) {
  __shared__ float xs[HID];
  int b = blockIdx.x;
  for (int k = threadIdx.x; k < HID; k += blockDim.x) xs[k] = X[(size_t)b*HID + k];
  __syncthreads();
  int j = threadIdx.x;
  if (j < HID) {
    const float4* wr = (const float4*)(W + (size_t)j*HID);
    float acc = 0.f;
    #pragma unroll 7
    for (int k4 = 0; k4 < HID/4; ++k4) {
      float4 w4 = wr[k4];
      acc += xs[4*k4+0]*w4.x + xs[4*k4+1]*w4.y + xs[4*k4+2]*w4.z + xs[4*k4+3]*w4.w;
    }
    float v = (acc + bias[j]) * 0.9995003746f;   // 1/sqrt(1+1e-3)
    Y[(size_t)b*HID + j] = g[j]*v + beta[j];
  }
}

// ---- prologue: xg0T[c][b] = (z @ Wih0.T + bih0)^T  (constant over T) ----
__global__ __launch_bounds__(256)
void xg0v2_kernel(const float* __restrict__ Z, const float* __restrict__ Wih,
                  const float* __restrict__ bih, float* __restrict__ XGT) {
  __shared__ float zs[HID*4];
  int b0 = blockIdx.x << 2;
  for (int idx = threadIdx.x; idx < HID*4; idx += 256) {
    int k = idx >> 2, i = idx & 3;
    zs[idx] = Z[(size_t)(b0+i)*HID + k];
  }
  __syncthreads();
  for (int c = threadIdx.x; c < G3; c += 256) {
    const float4* wr = (const float4*)(Wih + (size_t)c*HID);
    float a0=0.f,a1=0.f,a2=0.f,a3=0.f;
    for (int k4 = 0; k4 < HID/4; ++k4) {
      float4 w = wr[k4];
      const float* zp = zs + (k4<<4);
      a0=fmaf(w.x,zp[0],a0);  a1=fmaf(w.x,zp[1],a1);  a2=fmaf(w.x,zp[2],a2);  a3=fmaf(w.x,zp[3],a3);
      a0=fmaf(w.y,zp[4],a0);  a1=fmaf(w.y,zp[5],a1);  a2=fmaf(w.y,zp[6],a2);  a3=fmaf(w.y,zp[7],a3);
      a0=fmaf(w.z,zp[8],a0);  a1=fmaf(w.z,zp[9],a1);  a2=fmaf(w.z,zp[10],a2); a3=fmaf(w.z,zp[11],a3);
      a0=fmaf(w.w,zp[12],a0); a1=fmaf(w.w,zp[13],a1); a2=fmaf(w.w,zp[14],a2); a3=fmaf(w.w,zp[15],a3);
    }
    float bb = bih[c];
    XGT[(size_t)c*Bsz + b0+0] = a0 + bb;
    XGT[(size_t)c*Bsz + b0+1] = a1 + bb;
    XGT[(size_t)c*Bsz + b0+2] = a2 + bb;
    XGT[(size_t)c*Bsz + b0+3] = a3 + bb;
  }
}

// ---- prologue: per-block contiguous weight slices ----
// Wt2[(stage*NB + j)*WSL + ck*192 + k*24 + (g*8+cl)] = Wsrc[(g*REC + j*8 + cl)*REC + ck*8 + k]
__global__ __launch_bounds__(256)
void wtrans_kernel(const float* __restrict__ Whh0, const float* __restrict__ Wih1,
                   const float* __restrict__ Whh1, float* __restrict__ Wt2) {
  int blk = blockIdx.x;                  // 3*61
  int stage = blk / NB, j = blk - stage*NB;
  const float* Wsrc = (stage==0) ? Whh0 : (stage==1) ? Wih1 : Whh1;
  float* dst = Wt2 + (size_t)blk*WSL;
  for (int idx = threadIdx.x; idx < WSL; idx += 256) {
    int ck = idx / 192, rem = idx - ck*192;
    int k = rem / 24, r = rem - k*24;
    int g = r >> 3, cl = r & 7;
    dst[idx] = Wsrc[(size_t)(g*REC + j*8 + cl)*REC + ck*8 + k];
  }
}

// ---- acc[24] += AT[:,b] @ W-slice (24 colgates), K=488 ----
// AT layout [k][512]: per-k A-loads wave-coalesced; depth-1 chunk prefetch.
// W read via BLOCK-UNIFORM addresses from global -> compiler emits s_load
// (scalar cache + SGPR operand in v_fma): zero LDS traffic in the K-loop.
__device__ __forceinline__ void gemm24s(const float* __restrict__ AT, int b,
                                        const float* __restrict__ wp,
                                        float (&acc)[24])
{
  float av[KT], nv[KT];
  #pragma unroll
  for (int k = 0; k < KT; ++k) av[k] = AT[(size_t)k*Bsz + b];
  for (int ck = 0; ck < NCH; ++ck) {
    if (ck + 1 < NCH) {
      const float* src = AT + (size_t)(ck+1)*KT*Bsz + b;
      #pragma unroll
      for (int k = 0; k < KT; ++k) nv[k] = src[(size_t)k*Bsz];
    }
    const float* w = wp + ck*192;        // block-uniform -> scalar loads
    #pragma unroll
    for (int k = 0; k < KT; ++k) {
      float a = av[k];
      #pragma unroll
      for (int r = 0; r < 24; ++r)
        acc[r] = fmaf(a, w[k*24 + r], acc[r]);
    }
    #pragma unroll
    for (int k = 0; k < KT; ++k) av[k] = nv[k];
  }
}

// ---- persistent kernel: 4-stage time pipeline, 215 blocks x 512 threads ----
// [0,61): GRU0 t=s | [61,122): GRU1 x-pass t=s-1 | [122,183): GRU1 h-pass t=s-2
// | [183,215): cell t=s-3.  Recurrent states TRANSPOSED [c][b]; hc normal.
__global__ __launch_bounds__(512)
void pers_kernel(const float* __restrict__ xg0T,
                 float* __restrict__ h0T, float* __restrict__ h1T,
                 float* __restrict__ xg1T, float* __restrict__ hc,
                 float* __restrict__ out,
                 const float* __restrict__ Wt2,
                 const float* __restrict__ bhh0,
                 const float* __restrict__ bih1, const float* __restrict__ bhh1,
                 const float* __restrict__ cWih, const float* __restrict__ cWhh,
                 const float* __restrict__ cb, int* __restrict__ bar)
{
  __shared__ CellSmem S;
  const int blk = blockIdx.x;
  const int tid = threadIdx.x;
  const int stage = (blk < NB) ? 0 : (blk < 2*NB) ? 1 : (blk < 3*NB) ? 2 : 3;
  const int l = tid & 63, w = tid >> 6;
  const float* wslice = Wt2 + (size_t)blk*WSL;   // block-uniform base

  for (int s = 0; s < NSLOT; ++s) {
    if (stage == 0) {                    // ---------- GRU0, t = s ----------
      if (s < TT) {
        int j = blk;
        const float* hprevT = h0T + (size_t)((s+1)&1)*REC*Bsz;
        float*       hnewT  = h0T + (size_t)(s&1)*REC*Bsz;
        float acc[24] = {0};
        gemm24s(hprevT, tid, wslice, acc);
        int b = tid, c0 = j*8;
        #pragma unroll
        for (int cl = 0; cl < 8; ++cl) {
          int c = c0 + cl;
          float xrv = xg0T[(size_t)c*Bsz + b];
          float xzv = xg0T[(size_t)(REC+c)*Bsz + b];
          float xnv = xg0T[(size_t)(2*REC+c)*Bsz + b];
          float r = sigmoidf_(xrv + acc[cl]      + bhh0[c]);
          float z = sigmoidf_(xzv + acc[8+cl]    + bhh0[REC+c]);
          float n = tanhf   (xnv + r*(acc[16+cl] + bhh0[2*REC+c]));
          hnewT[(size_t)c*Bsz + b] = (1.f-z)*n + z*hprevT[(size_t)c*Bsz + b];
        }
      }
    } else if (stage == 1) {             // ---------- GRU1 x-pass, t = s-1 ----------
      if (s >= 1 && s <= TT) {
        int t1 = s - 1;
        const float* xT   = h0T  + (size_t)(t1&1)*REC*Bsz;
        float*       xgwT = xg1T + (size_t)(t1&1)*G3*Bsz;
        float acc[24] = {0};
        gemm24s(xT, tid, wslice, acc);
        int b = tid, c0 = (blk - NB)*8;
        #pragma unroll
        for (int cl = 0; cl < 8; ++cl) {
          int c = c0 + cl;
          xgwT[(size_t)c*Bsz + b]         = acc[cl];
          xgwT[(size_t)(REC+c)*Bsz + b]   = acc[8+cl];
          xgwT[(size_t)(2*REC+c)*Bsz + b] = acc[16+cl];
        }
      }
    } else if (stage == 2) {             // ---------- GRU1 h-pass, t = s-2 ----------
      if (s >= 2 && s <= TT+1) {
        int t2 = s - 2;
        const float* hprevT = h1T  + (size_t)((t2+1)&1)*REC*Bsz;
        float*       hnewT  = h1T  + (size_t)(t2&1)*REC*Bsz;
        const float* xgrT   = xg1T + (size_t)(t2&1)*G3*Bsz;
        float acc[24] = {0};
        gemm24s(hprevT, tid, wslice, acc);
        int b = tid, c0 = (blk - 2*NB)*8;
        #pragma unroll
        for (int cl = 0; cl < 8; ++cl) {
          int c = c0 + cl;
          float xrv = xgrT[(size_t)c*Bsz + b];
          float xzv = xgrT[(size_t)(REC+c)*Bsz + b];
          float xnv = xgrT[(size_t)(2*REC+c)*Bsz + b];
          float r = sigmoidf_(xrv + acc[cl]   + bih1[c]     + bhh1[c]);
          float z = sigmoidf_(xzv + acc[8+cl] + bih1[REC+c] + bhh1[REC+c]);
          float n = tanhf   (xnv + bih1[2*REC+c] + r*(acc[16+cl] + bhh1[2*REC+c]));
          hnewT[(size_t)c*Bsz + b] = (1.f-z)*n + z*hprevT[(size_t)c*Bsz + b];
        }
      }
    } else {                             // ---------- custom cell, t = s-3 ----------
      if (s >= 3) {
        int t3 = s - 3;
        int b0 = (blk - 3*NB) << 4;      // 16 items per block
        const float* xT = h1T + (size_t)(t3&1)*REC*Bsz;
        const float* hp = hc  + (size_t)((t3+1)&1)*Bsz*NC;
        float*       hn = hc  + (size_t)(t3&1)*Bsz*NC;
        // stage x rows from transposed slab: idx = [k][it], 16-lane segments
        for (int idx = tid; idx < 16*REC; idx += 512) {
          int k = idx >> 4, it = idx & 15;
          S.xs[it][k] = xT[(size_t)k*Bsz + b0 + it];
        }
        if (l < NC) {
          #pragma unroll
          for (int q = 0; q < 2; ++q) {
            int it = (w<<1) + q;
            S.hs[it][l] = hp[(size_t)(b0+it)*NC + l];
          }
        }
        __syncthreads();
        for (int q = 0; q < 2; ++q) {
          int it = (w<<1) + q;
          int b = b0 + it;
          float v = -1e30f, u = 0.f, hpc = 0.f;
          if (l < NC) {
            const float4* wr4 = (const float4*)(cWih + (size_t)l*REC);
            const float4* wz4 = (const float4*)(cWih + (size_t)(NC+l)*REC);
            const float4* wn4 = (const float4*)(cWih + (size_t)(2*NC+l)*REC);
            const float4* xs4 = (const float4*)(S.xs[it]);
            float xr=0.f, xz=0.f, xn=0.f;
            #pragma unroll 2
            for (int k4 = 0; k4 < REC/4; ++k4) {
              float4 xv = xs4[k4];
              float4 wa = wr4[k4], wb = wz4[k4], wc = wn4[k4];
              xr += wa.x*xv.x + wa.y*xv.y + wa.z*xv.z + wa.w*xv.w;
              xz += wb.x*xv.x + wb.y*xv.y + wb.z*xv.z + wb.w*xv.w;
              xn += wc.x*xv.x + wc.y*xv.y + wc.z*xv.z + wc.w*xv.w;
            }
            float hr=0.f, hz=0.f;
            for (int k = 0; k < NC; ++k) {
              float hv = S.hs[it][k];
              hr = fmaf(hv, cWhh[(size_t)l*NC + k], hr);
              hz = fmaf(hv, cWhh[(size_t)(NC+l)*NC + k], hz);
            }
            float r = sigmoidf_(xr + hr + cb[l]);
            u       = sigmoidf_(xz + hz + cb[NC+l]);
            hpc = S.hs[it][l];
            S.rh[it][l] = r * hpc;       // reference: (r*h) @ Whh_n.T
            v = xn;
          }
          __syncthreads();
          if (l < NC) {
            float hnn = 0.f;
            for (int k = 0; k < NC; ++k)
              hnn = fmaf(S.rh[it][k], cWhh[(size_t)(2*NC+l)*NC + k], hnn);
            v = v + hnn + cb[2*NC+l];
          }
          float m = v;
          #pragma unroll
          for (int o = 32; o; o >>= 1) m = fmaxf(m, __shfl_xor(m, o));
          float e = (l < NC) ? __expf(v - m) : 0.f;
          float ss = e;
          #pragma unroll
          for (int o = 32; o; o >>= 1) ss += __shfl_xor(ss, o);
          if (l < NC) {
            float h2 = (1.f - u)*(e/ss) + u*hpc;
            hn[(size_t)b*NC + l] = h2;
            out[((size_t)b*TT + t3)*NC + l] = h2;
          }
          __syncthreads();
        }
      }
    }
    gbar(bar, NGRID*(s+1));
  }
}

extern "C" void kernel_launch(void* const* d_in, const int* in_sizes, int n_in,
                              void* d_out, int out_size, void* d_ws, size_t ws_size,
                              hipStream_t stream) {
  const float* z_in  = (const float*)d_in[0];
  const float* W0    = (const float*)d_in[1];
  const float* b0    = (const float*)d_in[2];
  const float* g0    = (const float*)d_in[3];
  const float* beta0 = (const float*)d_in[4];
  const float* W1    = (const float*)d_in[5];
  const float* b1    = (const float*)d_in[6];
  const float* g1    = (const float*)d_in[7];
  const float* beta1 = (const float*)d_in[8];
  const float* Wih0  = (const float*)d_in[9];
  const float* Whh0  = (const float*)d_in[10];
  const float* bih0  = (const float*)d_in[11];
  const float* bhh0  = (const float*)d_in[12];
  const float* Wih1  = (const float*)d_in[13];
  const float* Whh1  = (const float*)d_in[14];
  const float* bih1  = (const float*)d_in[15];
  const float* bhh1  = (const float*)d_in[16];
  const float* cWih  = (const float*)d_in[17];
  const float* cWhh  = (const float*)d_in[18];
  const float* cbih  = (const float*)d_in[19];
  float* out = (float*)d_out;

  float* ws   = (float*)d_ws;
  int*   bar  = (int*)ws;                            // 256 slots (zeroed)
  float* h0T  = ws   + 256;                          // 2*REC*Bsz (zeroed)
  float* h1T  = h0T  + 2*(size_t)REC*Bsz;            // 2*REC*Bsz (zeroed)
  float* hcb  = h1T  + 2*(size_t)REC*Bsz;            // 2*Bsz*NC  (zeroed)
  float* xg1T = hcb  + 2*(size_t)Bsz*NC;             // 2*G3*Bsz
  float* xg0T = xg1T + 2*(size_t)G3*Bsz;             // G3*Bsz
  float* z1   = xg0T + (size_t)G3*Bsz;               // Bsz*HID
  float* z2   = z1   + (size_t)Bsz*HID;              // Bsz*HID
  float* Wt2  = z2   + (size_t)Bsz*HID;              // 3*NB*WSL = 8.6 MB

  size_t zero_floats = 256 + 4*(size_t)REC*Bsz + 2*(size_t)Bsz*NC;
  hipMemsetAsync(ws, 0, zero_floats*sizeof(float), stream);

  dense_bn_kernel<<<Bsz, 256, 0, stream>>>(z_in, W0, b0, g0, beta0, z1);
  dense_bn_kernel<<<Bsz, 256, 0, stream>>>(z1,   W1, b1, g1, beta1, z2);
  xg0v2_kernel   <<<128, 256, 0, stream>>>(z2, Wih0, bih0, xg0T);
  wtrans_kernel  <<<3*NB, 256, 0, stream>>>(Whh0, Wih1, Whh1, Wt2);

  pers_kernel<<<NGRID, 512, 0, stream>>>(xg0T, h0T, h1T, xg1T, hcb, out,
                                         Wt2, bhh0, bih1, bhh1, cWih, cWhh, cbih, bar);
}